// Round 12
// baseline (3389.774 us; speedup 1.0000x reference)
//
#include <hip/hip_runtime.h>

#define TT 512
#define BSZ 64
#define DD 512
#define HH 512
#define NGROUP 4
#define GBLK 64        // blocks per group
#define GBATCH 16      // batches per group
#define NT 512         // threads per block

// part layout strides (floats), engineered conflict-free:
//  write lanes (4 sp x 2 par x 8 u): 2-way aliasing (free)
//  cell lanes (16 bbu x 8 jju): 2-way aliasing (free)
#define PART_SP 40
#define PART_BB 1284   // >= 32*40, and PART_BB % 32 == 4

struct Params {
    const float* X;
    const float* Wx[4];   // W_xi, W_xf, W_xo, W_xc   [D][H] row-major
    const float* Wh[4];   // W_hi, W_hf, W_ho, W_hc   [H][H] row-major
    const float* bias[4]; // b_i, b_f, b_o, b_c       [H]
    float* Y;             // [B][T][H]
    float* hbuf;          // ws: 2 * B * H floats (double buffer)
    unsigned int* ctr;    // ws: [group][octet] publish counters (spread x8)
};

__device__ __forceinline__ float fast_sigmoid(float x) {
    return 1.0f / (1.0f + __expf(-x));
}

__device__ __forceinline__ float fast_tanh(float x) {
    float ax = fabsf(x);
    float e  = __expf(-2.0f * ax);
    float r  = (1.0f - e) / (1.0f + e);
    return copysignf(r, x);
}

// xor-8 pair-sum on the VALU pipe via DPP row_ror:8 (lane l <-> l^8 within each
// 16-lane row). MUST stay off the LDS pipe.
__device__ __forceinline__ float dpp_xor8_add(float v) {
    int pv = __builtin_amdgcn_update_dpp(0, __float_as_int(v),
                                         0x128 /*row_ror:8*/, 0xf, 0xf, true);
    return v + __int_as_float(pv);
}

// hbuf/ctr are accessed ONLY via cache-bypassing (agent-scope relaxed) ops in
// the main kernel, so the init writes must also be write-through.
__global__ void init_ws(float* hbuf, unsigned int* ctr) {
    int i = blockIdx.x * blockDim.x + threadIdx.x;
    int stride = gridDim.x * blockDim.x;
    for (int k = i; k < 2 * BSZ * HH; k += stride)
        __hip_atomic_store(&hbuf[k], 0.0f, __ATOMIC_RELAXED, __HIP_MEMORY_SCOPE_AGENT);
    if (i < 8 * 64)
        __hip_atomic_store(&ctr[i], 0u, __ATOMIC_RELAXED, __HIP_MEMORY_SCOPE_AGENT);
}

// Persistent LSTM, R12: OCTET-GRANULAR publish/detect on the R11 base (3345us).
// 256 blocks x 512 threads, 144.3 KB LDS -> 1 block/CU.
//
// R11 established: wave wv consumes h columns [64wv,64wv+64) and stages them
// itself. Those columns are produced by ONLY 8 blocks (octet wv: k in
// [8wv,8wv+8)). R11 still polled the GROUP counter (need 64t) — waiting on the
// group's globally slowest block when only 8 producers matter. R12: each block
// publishes (relaxed fetch_add, same access type as R6-proven) to ITS OCTET's
// counter ctr[g*64 + (k>>3)*8]; wave wv polls ctr[g*64 + wv*8] for 8t. Detect
// gates on slowest-of-8 instead of slowest-of-64; waves desync further,
// deepening R11's cross-wave latency overlap. s_sleep(4)->s_sleep(1).
//
// HARD RULES (paid for in container kills / regressions):
//  - NT=1024 POISONED (R3/R4: 64-VGPR pathology -> 75GB spill).
//  - >1 block/CU residency FORBIDDEN (R5); hipLaunchCooperativeKernel
//    FORBIDDEN (R8: graph-capture).
//  - Do NOT move work across the spin (R7: pre-spin work is free).
//  - R9's store+ballot slot protocol killed a container (unexplained);
//    this round keeps the PROVEN access types (fetch_add publish, single-
//    address relaxed spin) and the proven init-zeroed counter region — only
//    the counter COUNT changes (4 -> 32, spread 32B apart).
//
// COHERENCE: unchanged. Producer h-stores write-through relaxed-agent (IF);
// B3 __syncthreads drains vmcnt (h at IF) before tid0's fetch_add; octet
// counter >= 8t observed => those 8 blocks' h(t-1) at IF => bypass loads see
// them. hs stage->read wave-local; part via B2; WAR via the step-t lockstep
// (a block's step-t+1 hbuf writes only follow its waves observing 8t, i.e.
// its sources' step-t publishes; its OWN buffer-slot writes are gated by its
// own cell waves which sit behind B2/B1 with all its waves).
__global__ __launch_bounds__(NT, 1) void lstm_persist(Params p) {
    __shared__ float xs[GBATCH * DD];        // 32 KB: x_t, 16 batches
    __shared__ float hs[GBATCH * HH];        // 32 KB: h_{t-1}, 16 batches
    __shared__ float part[16 * PART_BB];     // 80.25 KB: partials

    const int bid  = blockIdx.x;
    // XCD-pair swizzle (XCD assumed = bid & 7)
    const int g    = (bid & 7) >> 1;               // group 0..3 -> XCDs {2g,2g+1}
    const int k    = ((bid >> 3) << 1) | (bid & 1); // block-in-group 0..63
    const int tid  = threadIdx.x;
    const int u    = tid & 7;              // unit-in-block 0..7
    const int s    = tid >> 3;             // K-slice 0..63
    const int kb   = s * 8;                // K start (8 rows/thread)
    const int jc   = k * 8 + u;            // column in each gate's weight matrix
    const int b0   = g * GBATCH;
    const int l    = tid & 63;             // lane in wave
    const int wv   = tid >> 6;             // wave 0..7

    // ---- one-time: weights into registers (4 gates x 8 k, x and h) ----
    float4 wx4[4][2], wh4[4][2];
#pragma unroll
    for (int g4 = 0; g4 < 4; ++g4) {
        const float* WxG = p.Wx[g4];
        const float* WhG = p.Wh[g4];
#pragma unroll
        for (int k4 = 0; k4 < 2; ++k4) {
            int kk = kb + k4 * 4;
            wx4[g4][k4] = make_float4(WxG[(kk + 0) * HH + jc], WxG[(kk + 1) * HH + jc],
                                      WxG[(kk + 2) * HH + jc], WxG[(kk + 3) * HH + jc]);
            wh4[g4][k4] = make_float4(WhG[(kk + 0) * HH + jc], WhG[(kk + 1) * HH + jc],
                                      WhG[(kk + 2) * HH + jc], WhG[(kk + 3) * HH + jc]);
        }
    }

    // Cell-update thread state (threads 0..127): (batch bbu, unit jju)
    const int bbu = tid >> 3;              // 0..15 (for tid<128)
    const int jju = tid & 7;
    const int ju  = k * 8 + jju;
    float cst = 0.0f;
    float bI = 0.f, bF = 0.f, bO = 0.f, bC = 0.f;
    if (tid < 128) {
        bI = p.bias[0][ju];
        bF = p.bias[1][ju];
        bO = p.bias[2][ju];
        bC = p.bias[3][ju];
    }

    unsigned int* ctr_pub  = p.ctr + g * 64 + (k >> 3) * 8;  // my octet's counter
    unsigned int* ctr_poll = p.ctr + g * 64 + wv * 8;        // my source octet
    const float4* xsrc = (const float4*)p.X;
    float4* xs4 = (float4*)xs;
    float4* hs4 = (float4*)hs;
    unsigned long long* hsu = (unsigned long long*)hs;

#define ACC4(A, V, W) \
    A = fmaf((V).x, (W).x, A); A = fmaf((V).y, (W).y, A); \
    A = fmaf((V).z, (W).z, A); A = fmaf((V).w, (W).w, A);

    for (int t = 0; t < TT; ++t) {
        // ---- 1. stage x_t (no cross-block dependency): 4 float4/thread ----
#pragma unroll
        for (int uu = 0; uu < 4; ++uu) {
            int idx = tid + uu * NT;           // 0..2047 (float4 index)
            int b   = idx >> 7;                // 0..15
            int dd  = idx & 127;               // float4 within row
            xs4[b * 128 + dd] = xsrc[((size_t)(b0 + b) * TT + t) * 128 + dd];
        }
        __syncthreads();                       // B1: xs ready (cross-wave)

        // ---- 2. x-projection: each b128 broadcast feeds 16 FMAs ----
        float acc[4][16];
#pragma unroll
        for (int g4 = 0; g4 < 4; ++g4)
#pragma unroll
            for (int bb = 0; bb < 16; ++bb) acc[g4][bb] = 0.0f;
#pragma unroll
        for (int k4 = 0; k4 < 2; ++k4) {
#pragma unroll
            for (int bb = 0; bb < 16; ++bb) {
                float4 xv = xs4[bb * 128 + s * 2 + k4];   // 8-lane broadcast
                ACC4(acc[0][bb], xv, wx4[0][k4]);
                ACC4(acc[1][bb], xv, wx4[1][k4]);
                ACC4(acc[2][bb], xv, wx4[2][k4]);
                ACC4(acc[3][bb], xv, wx4[3][k4]);
                if ((bb & 3) == 3) __builtin_amdgcn_sched_barrier(0);
            }
        }

        // ---- 3. PER-WAVE wait: lane0 holds its wave on its SOURCE OCTET's
        //      counter (8 producers, need 8t) — not the whole group ----
        if (l == 0) {
            const unsigned int need = (unsigned int)(8 * t);
            while (__hip_atomic_load(ctr_poll, __ATOMIC_RELAXED, __HIP_MEMORY_SCOPE_AGENT) < need) {
                __builtin_amdgcn_s_sleep(1);
            }
        }
        // (wave reconverges here — no cross-wave barrier)

        // ---- 4. PER-WAVE h-stage: wave wv stages its own region
        //      h[.][64wv..64wv+64) = exactly what its slices read ----
        {
            const unsigned long long* hsrc =
                (const unsigned long long*)(p.hbuf + (size_t)(t & 1) * BSZ * HH);
            unsigned long long tmpu[8];
#pragma unroll
            for (int uu = 0; uu < 8; ++uu) {
                int idx = l + uu * 64;         // 0..511
                int b   = idx >> 5;            // 0..15
                int d   = idx & 31;            // u64 within the 32-u64 region
                tmpu[uu] = __hip_atomic_load(&hsrc[(size_t)(b0 + b) * 256 + 32 * wv + d],
                                             __ATOMIC_RELAXED, __HIP_MEMORY_SCOPE_AGENT);
            }
#pragma unroll
            for (int uu = 0; uu < 8; ++uu) {
                int idx = l + uu * 64;
                int b   = idx >> 5;
                int d   = idx & 31;
                hsu[b * 256 + 32 * wv + d] = tmpu[uu];
            }
        }
        // (stage->read is wave-local: compiler's lgkmcnt suffices, no barrier)

        // ---- 5. recurrent FMAs (reads only this wave's staged region) ----
#pragma unroll
        for (int k4 = 0; k4 < 2; ++k4) {
#pragma unroll
            for (int bb = 0; bb < 16; ++bb) {
                float4 hv = hs4[bb * 128 + s * 2 + k4];   // 8-lane broadcast
                ACC4(acc[0][bb], hv, wh4[0][k4]);
                ACC4(acc[1][bb], hv, wh4[1][k4]);
                ACC4(acc[2][bb], hv, wh4[2][k4]);
                ACC4(acc[3][bb], hv, wh4[3][k4]);
                if ((bb & 3) == 3) __builtin_amdgcn_sched_barrier(0);
            }
        }

        // ---- 6. DPP xor8 pair-sum (VALU), then write 32 sp-slices.
        //      s even -> gates {0,1}; s odd -> {2,3}. Static acc indices. ----
#pragma unroll
        for (int g4 = 0; g4 < 4; ++g4)
#pragma unroll
            for (int bb = 0; bb < 16; ++bb)
                acc[g4][bb] = dpp_xor8_add(acc[g4][bb]);
        {
            const int sp = s >> 1;             // 0..31
            float* dst = &part[sp * PART_SP + (s & 1) * 16 + u];
            if ((s & 1) == 0) {
#pragma unroll
                for (int bb = 0; bb < 16; ++bb) {
                    dst[bb * PART_BB + 0] = acc[0][bb];
                    dst[bb * PART_BB + 8] = acc[1][bb];
                }
            } else {
#pragma unroll
                for (int bb = 0; bb < 16; ++bb) {
                    dst[bb * PART_BB + 0] = acc[2][bb];
                    dst[bb * PART_BB + 8] = acc[3][bb];
                }
            }
        }
        __syncthreads();                       // B2: part ready (cross-wave)

        // ---- 7. cell update (2 waves: 16 batches x 8 units); Y deferred ----
        float hout = 0.0f;
        if (tid < 128) {
            float v0 = bI, v1 = bF, v2 = bO, v3 = bC;
            const float* pr = &part[bbu * PART_BB + jju];
#pragma unroll
            for (int ss = 0; ss < 32; ++ss) {
                v0 += pr[ss * PART_SP + 0];
                v1 += pr[ss * PART_SP + 8];
                v2 += pr[ss * PART_SP + 16];
                v3 += pr[ss * PART_SP + 24];
            }
            float I  = fast_sigmoid(v0);
            float F  = fast_sigmoid(v1);
            float O  = fast_sigmoid(v2);
            float Cd = fast_tanh(v3);
            cst = fmaf(F, cst, I * Cd);
            hout = O * fast_tanh(cst);
            // write-through to the IF (coherence point)
            __hip_atomic_store(&p.hbuf[(size_t)((t + 1) & 1) * BSZ * HH + (b0 + bbu) * HH + ju],
                               hout, __ATOMIC_RELAXED, __HIP_MEMORY_SCOPE_AGENT);
        }
        __syncthreads();                       // B3: drains vmcnt (h at IF)

        // ---- 8. publish: tid0 RELAXED fetch_add to MY OCTET's counter ----
        if (tid == 0) {
            __hip_atomic_fetch_add(ctr_pub, 1u, __ATOMIC_RELAXED, __HIP_MEMORY_SCOPE_AGENT);
        }

        // ---- 9. Y store AFTER publish: HBM ack hides under next pre-spin work ----
        if (tid < 128) {
            p.Y[((size_t)(b0 + bbu) * TT + t) * HH + ju] = hout;
        }
    }
#undef ACC4
}

extern "C" void kernel_launch(void* const* d_in, const int* in_sizes, int n_in,
                              void* d_out, int out_size, void* d_ws, size_t ws_size,
                              hipStream_t stream) {
    Params p;
    p.X       = (const float*)d_in[0];
    p.Wx[0]   = (const float*)d_in[1];
    p.Wh[0]   = (const float*)d_in[2];
    p.bias[0] = (const float*)d_in[3];
    p.Wx[1]   = (const float*)d_in[4];
    p.Wh[1]   = (const float*)d_in[5];
    p.bias[1] = (const float*)d_in[6];
    p.Wx[2]   = (const float*)d_in[7];
    p.Wh[2]   = (const float*)d_in[8];
    p.bias[2] = (const float*)d_in[9];
    p.Wx[3]   = (const float*)d_in[10];
    p.Wh[3]   = (const float*)d_in[11];
    p.bias[3] = (const float*)d_in[12];
    p.Y       = (float*)d_out;
    p.hbuf    = (float*)d_ws;
    p.ctr     = (unsigned int*)((char*)d_ws + (size_t)2 * BSZ * HH * sizeof(float));

    // ws is poisoned 0xAA before every timed launch: zero h0 double-buffer + counters
    init_ws<<<64, 256, 0, stream>>>(p.hbuf, p.ctr);

    lstm_persist<<<dim3(256), dim3(NT), 0, stream>>>(p);
}

// Round 13
// 3096.562 us; speedup vs baseline: 1.0947x; 1.0947x over previous
//
#include <hip/hip_runtime.h>

#define TT 512
#define BSZ 64
#define DD 512
#define HH 512
#define NGROUP 4
#define GBLK 64        // blocks per group
#define GBATCH 16      // batches per group
#define NT 512         // threads per block

// part layout: [bb (stride 1192)][u (stride 148)][gate (stride 36)][sp 0..31]
// All strides ≡ 0 mod 4 -> b128-aligned reads.
// Writes (b32, 32 lanes: u 0..7 x sp window of 4): banks 20u+sp all-distinct -> conflict-free.
// Cell reads (b128, 64 lanes: bbu 2 x jju 8 x q 4): bases multiples of 4, each
// residue class hit exactly 8x -> uniform coverage = optimal 8-cycle, conflict-free.
#define PART_G 36
#define PART_U 148     // 4*36 + 4   (20 mod 32)
#define PART_BB 1192   // 8*148 + 8  (8 mod 32)

struct Params {
    const float* X;
    const float* Wx[4];   // W_xi, W_xf, W_xo, W_xc   [D][H] row-major
    const float* Wh[4];   // W_hi, W_hf, W_ho, W_hc   [H][H] row-major
    const float* bias[4]; // b_i, b_f, b_o, b_c       [H]
    float* Y;             // [B][T][H]
    float* hbuf;          // ws: 2 * B * H floats (double buffer)
    unsigned int* ctr;    // ws: NGROUP counters, 64-uint padded
};

__device__ __forceinline__ float fast_sigmoid(float x) {
    return 1.0f / (1.0f + __expf(-x));
}

__device__ __forceinline__ float fast_tanh(float x) {
    float ax = fabsf(x);
    float e  = __expf(-2.0f * ax);
    float r  = (1.0f - e) / (1.0f + e);
    return copysignf(r, x);
}

// xor-8 pair-sum on the VALU pipe via DPP row_ror:8 (lane l <-> l^8 within each
// 16-lane row). MUST stay off the LDS pipe.
__device__ __forceinline__ float dpp_xor8_add(float v) {
    int pv = __builtin_amdgcn_update_dpp(0, __float_as_int(v),
                                         0x128 /*row_ror:8*/, 0xf, 0xf, true);
    return v + __int_as_float(pv);
}

// quad butterfly sum (VALU pipe): quad_perm [1,0,3,2]=0xB1 then [2,3,0,1]=0x4E.
// After this, all 4 lanes of the quad hold the quad's total.
__device__ __forceinline__ float quad_sum(float v) {
    int a = __builtin_amdgcn_update_dpp(0, __float_as_int(v), 0xB1, 0xf, 0xf, true);
    v += __int_as_float(a);
    int b = __builtin_amdgcn_update_dpp(0, __float_as_int(v), 0x4E, 0xf, 0xf, true);
    v += __int_as_float(b);
    return v;
}

// hbuf/ctr are accessed ONLY via cache-bypassing (agent-scope relaxed) ops in
// the main kernel, so the init writes must also be write-through.
__global__ void init_ws(float* hbuf, unsigned int* ctr) {
    int i = blockIdx.x * blockDim.x + threadIdx.x;
    int stride = gridDim.x * blockDim.x;
    for (int k = i; k < 2 * BSZ * HH; k += stride)
        __hip_atomic_store(&hbuf[k], 0.0f, __ATOMIC_RELAXED, __HIP_MEMORY_SCOPE_AGENT);
    if (i < 8 * 64)
        __hip_atomic_store(&ctr[i], 0u, __ATOMIC_RELAXED, __HIP_MEMORY_SCOPE_AGENT);
}

// Persistent LSTM, R13: RESTRUCTURED REDUCTION EPILOGUE on the R11 base
// (3345us; R12's octet counters were a null -> reverted to R11's protocol).
// 256 blocks x 512 threads, 138.5 KB LDS -> 1 block/CU.
//
// R11's LDS budget/CU/step: ~1100 wave-instrs, of which part-writes (256) +
// cell scalar reads (256) = 512 — as much as all FMA-feeding reads — and the
// cell ran on 2 waves with 6 idle. R13: (a) part layout re-strided so writes
// are conflict-free and cell reads are b128 uniform-coverage (zero conflict);
// (b) cell spread over ALL 8 waves: thread (bbu, jju, q) reads 8 b128
// (q's 8-sp span x 4 gates), quad_perm DPP butterfly combines the 4 q-lanes
// (VALU pipe), activations computed redundantly in the quad (no divergence),
// q==0 stores h. Cell LDS 256->64 instrs, tail ~4x shorter. c-state is 4x
// redundant per quad (identical arithmetic, bitwise-same).
//
// HARD RULES (paid for in container kills / regressions):
//  - NT=1024 POISONED (R3/R4: 64-VGPR pathology -> 75GB spill).
//  - >1 block/CU residency FORBIDDEN (R5); hipLaunchCooperativeKernel
//    FORBIDDEN (R8: graph-capture).
//  - Do NOT move work across the spin (R7: pre-spin work is free).
//  - Protocol frozen at R11's proven form (group counter fetch_add publish,
//    per-wave lane0 relaxed spin, s_sleep(4)); R9-style novel protocols
//    quarantined; R12 octet granularity was a null.
//
// COHERENCE (proven R1-R12): h exchange is IF-coherent, ZERO fences.
// Producer: relaxed agent store (write-through). B3 __syncthreads drains
// vmcnt; tid0 relaxed fetch_add; consumers spin relaxed; h staged per-wave
// via relaxed agent u64 loads (wave-local stage->read, no barrier).
__global__ __launch_bounds__(NT, 1) void lstm_persist(Params p) {
    __shared__ float xs[GBATCH * DD];        // 32 KB: x_t, 16 batches
    __shared__ float hs[GBATCH * HH];        // 32 KB: h_{t-1}, 16 batches
    __shared__ float part[16 * PART_BB];     // 74.5 KB: partials

    const int bid  = blockIdx.x;
    // XCD-pair swizzle (XCD assumed = bid & 7)
    const int g    = (bid & 7) >> 1;               // group 0..3 -> XCDs {2g,2g+1}
    const int k    = ((bid >> 3) << 1) | (bid & 1); // block-in-group 0..63
    const int tid  = threadIdx.x;
    const int u    = tid & 7;              // unit-in-block 0..7
    const int s    = tid >> 3;             // K-slice 0..63
    const int kb   = s * 8;                // K start (8 rows/thread)
    const int jc   = k * 8 + u;            // column in each gate's weight matrix
    const int b0   = g * GBATCH;
    const int l    = tid & 63;             // lane in wave
    const int wv   = tid >> 6;             // wave 0..7

    // ---- one-time: weights into registers (4 gates x 8 k, x and h) ----
    float4 wx4[4][2], wh4[4][2];
#pragma unroll
    for (int g4 = 0; g4 < 4; ++g4) {
        const float* WxG = p.Wx[g4];
        const float* WhG = p.Wh[g4];
#pragma unroll
        for (int k4 = 0; k4 < 2; ++k4) {
            int kk = kb + k4 * 4;
            wx4[g4][k4] = make_float4(WxG[(kk + 0) * HH + jc], WxG[(kk + 1) * HH + jc],
                                      WxG[(kk + 2) * HH + jc], WxG[(kk + 3) * HH + jc]);
            wh4[g4][k4] = make_float4(WhG[(kk + 0) * HH + jc], WhG[(kk + 1) * HH + jc],
                                      WhG[(kk + 2) * HH + jc], WhG[(kk + 3) * HH + jc]);
        }
    }

    // Cell-update thread state (ALL 512 threads): (batch cb, unit cj, quarter cq)
    const int cb = tid >> 5;               // 0..15
    const int cj = (tid >> 2) & 7;         // 0..7
    const int cq = tid & 3;                // 0..3 (8-sp span owner)
    const int ju = k * 8 + cj;
    float cst = 0.0f;                      // 4x redundant per quad (identical math)
    const float bI = p.bias[0][ju];
    const float bF = p.bias[1][ju];
    const float bO = p.bias[2][ju];
    const float bC = p.bias[3][ju];

    unsigned int* ctrp = p.ctr + g * 64;
    const float4* xsrc = (const float4*)p.X;
    float4* xs4 = (float4*)xs;
    float4* hs4 = (float4*)hs;
    unsigned long long* hsu = (unsigned long long*)hs;
    const float* pb = &part[cb * PART_BB + cj * PART_U + cq * 8];

#define ACC4(A, V, W) \
    A = fmaf((V).x, (W).x, A); A = fmaf((V).y, (W).y, A); \
    A = fmaf((V).z, (W).z, A); A = fmaf((V).w, (W).w, A);

    for (int t = 0; t < TT; ++t) {
        // ---- 1. stage x_t (no cross-block dependency): 4 float4/thread ----
#pragma unroll
        for (int uu = 0; uu < 4; ++uu) {
            int idx = tid + uu * NT;           // 0..2047 (float4 index)
            int b   = idx >> 7;                // 0..15
            int dd  = idx & 127;               // float4 within row
            xs4[b * 128 + dd] = xsrc[((size_t)(b0 + b) * TT + t) * 128 + dd];
        }
        __syncthreads();                       // B1: xs ready (cross-wave)

        // ---- 2. x-projection: each b128 broadcast feeds 16 FMAs ----
        float acc[4][16];
#pragma unroll
        for (int g4 = 0; g4 < 4; ++g4)
#pragma unroll
            for (int bb = 0; bb < 16; ++bb) acc[g4][bb] = 0.0f;
#pragma unroll
        for (int k4 = 0; k4 < 2; ++k4) {
#pragma unroll
            for (int bb = 0; bb < 16; ++bb) {
                float4 xv = xs4[bb * 128 + s * 2 + k4];   // 8-lane broadcast
                ACC4(acc[0][bb], xv, wx4[0][k4]);
                ACC4(acc[1][bb], xv, wx4[1][k4]);
                ACC4(acc[2][bb], xv, wx4[2][k4]);
                ACC4(acc[3][bb], xv, wx4[3][k4]);
                if ((bb & 3) == 3) __builtin_amdgcn_sched_barrier(0);
            }
        }

        // ---- 3. PER-WAVE wait for h_{t-1}: lane0 holds its wave on the
        //      proven group counter (R11 protocol, frozen) ----
        if (l == 0) {
            const unsigned int need = (unsigned int)(GBLK * t);
            while (__hip_atomic_load(ctrp, __ATOMIC_RELAXED, __HIP_MEMORY_SCOPE_AGENT) < need) {
                __builtin_amdgcn_s_sleep(4);
            }
        }
        // (wave reconverges here — no cross-wave barrier)

        // ---- 4. PER-WAVE h-stage: wave wv stages its own region
        //      h[.][64wv..64wv+64) = exactly what its slices read ----
        {
            const unsigned long long* hsrc =
                (const unsigned long long*)(p.hbuf + (size_t)(t & 1) * BSZ * HH);
            unsigned long long tmpu[8];
#pragma unroll
            for (int uu = 0; uu < 8; ++uu) {
                int idx = l + uu * 64;         // 0..511
                int b   = idx >> 5;            // 0..15
                int d   = idx & 31;            // u64 within the 32-u64 region
                tmpu[uu] = __hip_atomic_load(&hsrc[(size_t)(b0 + b) * 256 + 32 * wv + d],
                                             __ATOMIC_RELAXED, __HIP_MEMORY_SCOPE_AGENT);
            }
#pragma unroll
            for (int uu = 0; uu < 8; ++uu) {
                int idx = l + uu * 64;
                int b   = idx >> 5;
                int d   = idx & 31;
                hsu[b * 256 + 32 * wv + d] = tmpu[uu];
            }
        }
        // (stage->read is wave-local: compiler's lgkmcnt suffices, no barrier)

        // ---- 5. recurrent FMAs (reads only this wave's staged region) ----
#pragma unroll
        for (int k4 = 0; k4 < 2; ++k4) {
#pragma unroll
            for (int bb = 0; bb < 16; ++bb) {
                float4 hv = hs4[bb * 128 + s * 2 + k4];   // 8-lane broadcast
                ACC4(acc[0][bb], hv, wh4[0][k4]);
                ACC4(acc[1][bb], hv, wh4[1][k4]);
                ACC4(acc[2][bb], hv, wh4[2][k4]);
                ACC4(acc[3][bb], hv, wh4[3][k4]);
                if ((bb & 3) == 3) __builtin_amdgcn_sched_barrier(0);
            }
        }

        // ---- 6. DPP xor8 pair-sum (VALU), then write 32 sp-slices into the
        //      conflict-free-strided part. s even -> gates {0,1}; s odd ->
        //      {2,3}. Static acc indices. ----
#pragma unroll
        for (int g4 = 0; g4 < 4; ++g4)
#pragma unroll
            for (int bb = 0; bb < 16; ++bb)
                acc[g4][bb] = dpp_xor8_add(acc[g4][bb]);
        {
            const int sp = s >> 1;             // 0..31
            float* dst = &part[u * PART_U + sp];
            if ((s & 1) == 0) {
#pragma unroll
                for (int bb = 0; bb < 16; ++bb) {
                    dst[bb * PART_BB + 0 * PART_G] = acc[0][bb];
                    dst[bb * PART_BB + 1 * PART_G] = acc[1][bb];
                }
            } else {
#pragma unroll
                for (int bb = 0; bb < 16; ++bb) {
                    dst[bb * PART_BB + 2 * PART_G] = acc[2][bb];
                    dst[bb * PART_BB + 3 * PART_G] = acc[3][bb];
                }
            }
        }
        __syncthreads();                       // B2: part ready (cross-wave)

        // ---- 7. cell update on ALL 8 waves: thread (cb, cj, cq) sums its
        //      8-sp span via 2 b128/gate, quad butterfly completes the sum ----
        float hout;
        {
            float4 r0, r1;
            r0 = *(const float4*)&pb[0 * PART_G + 0];
            r1 = *(const float4*)&pb[0 * PART_G + 4];
            float v0 = quad_sum(r0.x + r0.y + r0.z + r0.w + r1.x + r1.y + r1.z + r1.w) + bI;
            r0 = *(const float4*)&pb[1 * PART_G + 0];
            r1 = *(const float4*)&pb[1 * PART_G + 4];
            float v1 = quad_sum(r0.x + r0.y + r0.z + r0.w + r1.x + r1.y + r1.z + r1.w) + bF;
            r0 = *(const float4*)&pb[2 * PART_G + 0];
            r1 = *(const float4*)&pb[2 * PART_G + 4];
            float v2 = quad_sum(r0.x + r0.y + r0.z + r0.w + r1.x + r1.y + r1.z + r1.w) + bO;
            r0 = *(const float4*)&pb[3 * PART_G + 0];
            r1 = *(const float4*)&pb[3 * PART_G + 4];
            float v3 = quad_sum(r0.x + r0.y + r0.z + r0.w + r1.x + r1.y + r1.z + r1.w) + bC;

            float I  = fast_sigmoid(v0);
            float F  = fast_sigmoid(v1);
            float O  = fast_sigmoid(v2);
            float Cd = fast_tanh(v3);
            cst = fmaf(F, cst, I * Cd);        // redundant x4 per quad, identical
            hout = O * fast_tanh(cst);
            if (cq == 0) {
                // write-through to the IF (coherence point)
                __hip_atomic_store(&p.hbuf[(size_t)((t + 1) & 1) * BSZ * HH + (b0 + cb) * HH + ju],
                                   hout, __ATOMIC_RELAXED, __HIP_MEMORY_SCOPE_AGENT);
            }
        }
        __syncthreads();                       // B3: drains vmcnt (h at IF)

        // ---- 8. publish: tid0 RELAXED fetch_add (R11 protocol, frozen) ----
        if (tid == 0) {
            __hip_atomic_fetch_add(ctrp, 1u, __ATOMIC_RELAXED, __HIP_MEMORY_SCOPE_AGENT);
        }

        // ---- 9. Y store AFTER publish: HBM ack hides under next pre-spin work ----
        if (cq == 0) {
            p.Y[((size_t)(b0 + cb) * TT + t) * HH + ju] = hout;
        }
    }
#undef ACC4
}

extern "C" void kernel_launch(void* const* d_in, const int* in_sizes, int n_in,
                              void* d_out, int out_size, void* d_ws, size_t ws_size,
                              hipStream_t stream) {
    Params p;
    p.X       = (const float*)d_in[0];
    p.Wx[0]   = (const float*)d_in[1];
    p.Wh[0]   = (const float*)d_in[2];
    p.bias[0] = (const float*)d_in[3];
    p.Wx[1]   = (const float*)d_in[4];
    p.Wh[1]   = (const float*)d_in[5];
    p.bias[1] = (const float*)d_in[6];
    p.Wx[2]   = (const float*)d_in[7];
    p.Wh[2]   = (const float*)d_in[8];
    p.bias[2] = (const float*)d_in[9];
    p.Wx[3]   = (const float*)d_in[10];
    p.Wh[3]   = (const float*)d_in[11];
    p.bias[3] = (const float*)d_in[12];
    p.Y       = (float*)d_out;
    p.hbuf    = (float*)d_ws;
    p.ctr     = (unsigned int*)((char*)d_ws + (size_t)2 * BSZ * HH * sizeof(float));

    // ws is poisoned 0xAA before every timed launch: zero h0 double-buffer + counters
    init_ws<<<64, 256, 0, stream>>>(p.hbuf, p.ctr);

    lstm_persist<<<dim3(256), dim3(NT), 0, stream>>>(p);
}

// Round 14
// 2856.547 us; speedup vs baseline: 1.1867x; 1.0840x over previous
//
#include <hip/hip_runtime.h>

#define TT 512
#define BSZ 64
#define DD 512
#define HH 512
#define NGROUP 4
#define GBLK 64        // blocks per group
#define GBATCH 16      // batches per group
#define NT 512         // threads per block

// part layout: [bb (stride 1192)][u (stride 148)][gate (stride 36)][sp 0..31]
// All strides ≡ 0 mod 4 -> b128-aligned reads.
// Writes (b32): banks 20u+sp all-distinct -> conflict-free.
// Cell reads (b128): bases multiples of 4, uniform residue coverage -> conflict-free.
#define PART_G 36
#define PART_U 148     // 4*36 + 4   (20 mod 32)
#define PART_BB 1192   // 8*148 + 8  (8 mod 32)

typedef float f32x2 __attribute__((ext_vector_type(2)));

struct Params {
    const float* X;
    const float* Wx[4];   // W_xi, W_xf, W_xo, W_xc   [D][H] row-major
    const float* Wh[4];   // W_hi, W_hf, W_ho, W_hc   [H][H] row-major
    const float* bias[4]; // b_i, b_f, b_o, b_c       [H]
    float* Y;             // [B][T][H]
    float* hbuf;          // ws: 2 * B * H floats (double buffer)
    unsigned int* ctr;    // ws: NGROUP counters, 64-uint padded
};

__device__ __forceinline__ float fast_sigmoid(float x) {
    return 1.0f / (1.0f + __expf(-x));
}

__device__ __forceinline__ float fast_tanh(float x) {
    float ax = fabsf(x);
    float e  = __expf(-2.0f * ax);
    float r  = (1.0f - e) / (1.0f + e);
    return copysignf(r, x);
}

// xor-8 pair-sum on the VALU pipe via DPP row_ror:8 (lane l <-> l^8 within each
// 16-lane row). MUST stay off the LDS pipe, and MUST run with all 64 lanes
// active (bound_ctrl reads 0 from EXEC-masked lanes).
__device__ __forceinline__ float dpp_xor8_add(float v) {
    int pv = __builtin_amdgcn_update_dpp(0, __float_as_int(v),
                                         0x128 /*row_ror:8*/, 0xf, 0xf, true);
    return v + __int_as_float(pv);
}

// quad butterfly sum (VALU pipe): quad_perm [1,0,3,2]=0xB1 then [2,3,0,1]=0x4E.
__device__ __forceinline__ float quad_sum(float v) {
    int a = __builtin_amdgcn_update_dpp(0, __float_as_int(v), 0xB1, 0xf, 0xf, true);
    v += __int_as_float(a);
    int b = __builtin_amdgcn_update_dpp(0, __float_as_int(v), 0x4E, 0xf, 0xf, true);
    v += __int_as_float(b);
    return v;
}

// hbuf/ctr are accessed ONLY via cache-bypassing (agent-scope relaxed) ops in
// the main kernel, so the init writes must also be write-through.
__global__ void init_ws(float* hbuf, unsigned int* ctr) {
    int i = blockIdx.x * blockDim.x + threadIdx.x;
    int stride = gridDim.x * blockDim.x;
    for (int k = i; k < 2 * BSZ * HH; k += stride)
        __hip_atomic_store(&hbuf[k], 0.0f, __ATOMIC_RELAXED, __HIP_MEMORY_SCOPE_AGENT);
    if (i < 8 * 64)
        __hip_atomic_store(&ctr[i], 0u, __ATOMIC_RELAXED, __HIP_MEMORY_SCOPE_AGENT);
}

// Persistent LSTM, R14: PACKED FP32 FMA (v_pk_fma_f32) on the R13 base
// (3097us). 256 blocks x 512 threads, 138.5 KB LDS -> 1 block/CU.
//
// R13 hit VALUBusy 76.6% -> VALU-issue bound, dominated by 1024 scalar
// v_fma_f32/thread/step. CDNA4's 157.3 TF fp32 peak is the PACKED rate
// (v_pk_fma_f32 = 2 FMA/instr). R14 packs over the GATE axis: weights stored
// as gate-pairs (wxp[gp][k] = {w_2gp[k], w_2gp+1[k]}), acc2[2][16] f32x2
// (same 64-VGPR footprint as acc[4][16]), x/h broadcast element splat into
// both halves -> 2 pk-FMA per element instead of 4 scalar FMA. Per-gate
// k-order unchanged -> bitwise-identical numerics. FMA instrs/thread/step
// 1024 -> 512.
//
// CORRECTNESS INVARIANT: dpp_xor8 runs UNCONDITIONALLY (all 64 lanes active)
// BEFORE the even/odd-s store branch — DPP under divergence reads 0 from
// masked lanes and corrupts sums.
//
// HARD RULES (paid for in container kills / regressions):
//  - NT=1024 POISONED (R3/R4: 64-VGPR pathology -> 75GB spill).
//  - >1 block/CU residency FORBIDDEN (R5); hipLaunchCooperativeKernel
//    FORBIDDEN (R8: graph-capture).
//  - Do NOT move work across the spin (R7: pre-spin work is free).
//  - Protocol frozen at R11's proven form (group counter fetch_add publish,
//    per-wave lane0 relaxed spin); R12 octet granularity was a null.
//
// COHERENCE (proven R1-R13): h exchange is IF-coherent, ZERO fences.
// Producer: relaxed agent store (write-through). B3 __syncthreads drains
// vmcnt; tid0 relaxed fetch_add; consumers spin relaxed; h staged per-wave
// via relaxed agent u64 loads (wave-local stage->read, no barrier).
__global__ __launch_bounds__(NT, 1) void lstm_persist(Params p) {
    __shared__ float xs[GBATCH * DD];        // 32 KB: x_t, 16 batches
    __shared__ float hs[GBATCH * HH];        // 32 KB: h_{t-1}, 16 batches
    __shared__ float part[16 * PART_BB];     // 74.5 KB: partials

    const int bid  = blockIdx.x;
    // XCD-pair swizzle (XCD assumed = bid & 7)
    const int g    = (bid & 7) >> 1;               // group 0..3 -> XCDs {2g,2g+1}
    const int k    = ((bid >> 3) << 1) | (bid & 1); // block-in-group 0..63
    const int tid  = threadIdx.x;
    const int u    = tid & 7;              // unit-in-block 0..7
    const int s    = tid >> 3;             // K-slice 0..63
    const int kb   = s * 8;                // K start (8 rows/thread)
    const int jc   = k * 8 + u;            // column in each gate's weight matrix
    const int b0   = g * GBATCH;
    const int l    = tid & 63;             // lane in wave
    const int wv   = tid >> 6;             // wave 0..7

    // ---- one-time: weights into registers as GATE-PAIRS (pk operands) ----
    f32x2 wxp[2][8], whp[2][8];
#pragma unroll
    for (int gp = 0; gp < 2; ++gp) {
        const float* Wx0 = p.Wx[2 * gp];
        const float* Wx1 = p.Wx[2 * gp + 1];
        const float* Wh0 = p.Wh[2 * gp];
        const float* Wh1 = p.Wh[2 * gp + 1];
#pragma unroll
        for (int i = 0; i < 8; ++i) {
            int kk = kb + i;
            f32x2 a; a.x = Wx0[kk * HH + jc]; a.y = Wx1[kk * HH + jc];
            wxp[gp][i] = a;
            f32x2 b; b.x = Wh0[kk * HH + jc]; b.y = Wh1[kk * HH + jc];
            whp[gp][i] = b;
        }
    }

    // Cell-update thread state (ALL 512 threads): (batch cb, unit cj, quarter cq)
    const int cb = tid >> 5;               // 0..15
    const int cj = (tid >> 2) & 7;         // 0..7
    const int cq = tid & 3;                // 0..3 (8-sp span owner)
    const int ju = k * 8 + cj;
    float cst = 0.0f;                      // 4x redundant per quad (identical math)
    const float bI = p.bias[0][ju];
    const float bF = p.bias[1][ju];
    const float bO = p.bias[2][ju];
    const float bC = p.bias[3][ju];

    unsigned int* ctrp = p.ctr + g * 64;
    const float4* xsrc = (const float4*)p.X;
    float4* xs4 = (float4*)xs;
    float4* hs4 = (float4*)hs;
    unsigned long long* hsu = (unsigned long long*)hs;
    const float* pb = &part[cb * PART_BB + cj * PART_U + cq * 8];

// one broadcast element xval feeds both gate-pairs at k-index ki: 2 pk-FMA
#define PKFMA(W, ki, xval)                                                  \
    {                                                                       \
        f32x2 xx_; xx_.x = (xval); xx_.y = (xval);                          \
        acc2[0][bb] = __builtin_elementwise_fma(xx_, W[0][ki], acc2[0][bb]); \
        acc2[1][bb] = __builtin_elementwise_fma(xx_, W[1][ki], acc2[1][bb]); \
    }

    for (int t = 0; t < TT; ++t) {
        // ---- 1. stage x_t (no cross-block dependency): 4 float4/thread ----
#pragma unroll
        for (int uu = 0; uu < 4; ++uu) {
            int idx = tid + uu * NT;           // 0..2047 (float4 index)
            int b   = idx >> 7;                // 0..15
            int dd  = idx & 127;               // float4 within row
            xs4[b * 128 + dd] = xsrc[((size_t)(b0 + b) * TT + t) * 128 + dd];
        }
        __syncthreads();                       // B1: xs ready (cross-wave)

        // ---- 2. x-projection: each b128 broadcast feeds 8 pk-FMA (16 MAC) ----
        f32x2 acc2[2][16];
#pragma unroll
        for (int gp = 0; gp < 2; ++gp)
#pragma unroll
            for (int bb = 0; bb < 16; ++bb) { acc2[gp][bb].x = 0.0f; acc2[gp][bb].y = 0.0f; }
#pragma unroll
        for (int k4 = 0; k4 < 2; ++k4) {
#pragma unroll
            for (int bb = 0; bb < 16; ++bb) {
                float4 xv = xs4[bb * 128 + s * 2 + k4];   // 8-lane broadcast
                PKFMA(wxp, k4 * 4 + 0, xv.x);
                PKFMA(wxp, k4 * 4 + 1, xv.y);
                PKFMA(wxp, k4 * 4 + 2, xv.z);
                PKFMA(wxp, k4 * 4 + 3, xv.w);
                if ((bb & 3) == 3) __builtin_amdgcn_sched_barrier(0);
            }
        }

        // ---- 3. PER-WAVE wait for h_{t-1}: lane0 holds its wave on the
        //      proven group counter (R11 protocol, frozen) ----
        if (l == 0) {
            const unsigned int need = (unsigned int)(GBLK * t);
            while (__hip_atomic_load(ctrp, __ATOMIC_RELAXED, __HIP_MEMORY_SCOPE_AGENT) < need) {
                __builtin_amdgcn_s_sleep(4);
            }
        }
        // (wave reconverges here — no cross-wave barrier)

        // ---- 4. PER-WAVE h-stage: wave wv stages its own region
        //      h[.][64wv..64wv+64) = exactly what its slices read ----
        {
            const unsigned long long* hsrc =
                (const unsigned long long*)(p.hbuf + (size_t)(t & 1) * BSZ * HH);
            unsigned long long tmpu[8];
#pragma unroll
            for (int uu = 0; uu < 8; ++uu) {
                int idx = l + uu * 64;         // 0..511
                int b   = idx >> 5;            // 0..15
                int d   = idx & 31;            // u64 within the 32-u64 region
                tmpu[uu] = __hip_atomic_load(&hsrc[(size_t)(b0 + b) * 256 + 32 * wv + d],
                                             __ATOMIC_RELAXED, __HIP_MEMORY_SCOPE_AGENT);
            }
#pragma unroll
            for (int uu = 0; uu < 8; ++uu) {
                int idx = l + uu * 64;
                int b   = idx >> 5;
                int d   = idx & 31;
                hsu[b * 256 + 32 * wv + d] = tmpu[uu];
            }
        }
        // (stage->read is wave-local: compiler's lgkmcnt suffices, no barrier)

        // ---- 5. recurrent pk-FMAs (reads only this wave's staged region) ----
#pragma unroll
        for (int k4 = 0; k4 < 2; ++k4) {
#pragma unroll
            for (int bb = 0; bb < 16; ++bb) {
                float4 hv = hs4[bb * 128 + s * 2 + k4];   // 8-lane broadcast
                PKFMA(whp, k4 * 4 + 0, hv.x);
                PKFMA(whp, k4 * 4 + 1, hv.y);
                PKFMA(whp, k4 * 4 + 2, hv.z);
                PKFMA(whp, k4 * 4 + 3, hv.w);
                if ((bb & 3) == 3) __builtin_amdgcn_sched_barrier(0);
            }
        }

        // ---- 6. DPP xor8 pair-sum (VALU, ALL LANES ACTIVE), then the
        //      even/odd-s branch writes its 2 gates into part ----
#pragma unroll
        for (int gp = 0; gp < 2; ++gp)
#pragma unroll
            for (int bb = 0; bb < 16; ++bb) {
                acc2[gp][bb].x = dpp_xor8_add(acc2[gp][bb].x);
                acc2[gp][bb].y = dpp_xor8_add(acc2[gp][bb].y);
            }
        {
            const int sp = s >> 1;             // 0..31
            float* dst = &part[u * PART_U + sp];
            if ((s & 1) == 0) {
#pragma unroll
                for (int bb = 0; bb < 16; ++bb) {
                    dst[bb * PART_BB + 0 * PART_G] = acc2[0][bb].x;  // gate 0
                    dst[bb * PART_BB + 1 * PART_G] = acc2[0][bb].y;  // gate 1
                }
            } else {
#pragma unroll
                for (int bb = 0; bb < 16; ++bb) {
                    dst[bb * PART_BB + 2 * PART_G] = acc2[1][bb].x;  // gate 2
                    dst[bb * PART_BB + 3 * PART_G] = acc2[1][bb].y;  // gate 3
                }
            }
        }
        __syncthreads();                       // B2: part ready (cross-wave)

        // ---- 7. cell update on ALL 8 waves: thread (cb, cj, cq) sums its
        //      8-sp span via 2 b128/gate, quad butterfly completes the sum ----
        float hout;
        {
            float4 r0, r1;
            r0 = *(const float4*)&pb[0 * PART_G + 0];
            r1 = *(const float4*)&pb[0 * PART_G + 4];
            float v0 = quad_sum(r0.x + r0.y + r0.z + r0.w + r1.x + r1.y + r1.z + r1.w) + bI;
            r0 = *(const float4*)&pb[1 * PART_G + 0];
            r1 = *(const float4*)&pb[1 * PART_G + 4];
            float v1 = quad_sum(r0.x + r0.y + r0.z + r0.w + r1.x + r1.y + r1.z + r1.w) + bF;
            r0 = *(const float4*)&pb[2 * PART_G + 0];
            r1 = *(const float4*)&pb[2 * PART_G + 4];
            float v2 = quad_sum(r0.x + r0.y + r0.z + r0.w + r1.x + r1.y + r1.z + r1.w) + bO;
            r0 = *(const float4*)&pb[3 * PART_G + 0];
            r1 = *(const float4*)&pb[3 * PART_G + 4];
            float v3 = quad_sum(r0.x + r0.y + r0.z + r0.w + r1.x + r1.y + r1.z + r1.w) + bC;

            float I  = fast_sigmoid(v0);
            float F  = fast_sigmoid(v1);
            float O  = fast_sigmoid(v2);
            float Cd = fast_tanh(v3);
            cst = fmaf(F, cst, I * Cd);        // redundant x4 per quad, identical
            hout = O * fast_tanh(cst);
            if (cq == 0) {
                // write-through to the IF (coherence point)
                __hip_atomic_store(&p.hbuf[(size_t)((t + 1) & 1) * BSZ * HH + (b0 + cb) * HH + ju],
                                   hout, __ATOMIC_RELAXED, __HIP_MEMORY_SCOPE_AGENT);
            }
        }
        __syncthreads();                       // B3: drains vmcnt (h at IF)

        // ---- 8. publish: tid0 RELAXED fetch_add (R11 protocol, frozen) ----
        if (tid == 0) {
            __hip_atomic_fetch_add(ctrp, 1u, __ATOMIC_RELAXED, __HIP_MEMORY_SCOPE_AGENT);
        }

        // ---- 9. Y store AFTER publish: HBM ack hides under next pre-spin work ----
        if (cq == 0) {
            p.Y[((size_t)(b0 + cb) * TT + t) * HH + ju] = hout;
        }
    }
#undef PKFMA
}

extern "C" void kernel_launch(void* const* d_in, const int* in_sizes, int n_in,
                              void* d_out, int out_size, void* d_ws, size_t ws_size,
                              hipStream_t stream) {
    Params p;
    p.X       = (const float*)d_in[0];
    p.Wx[0]   = (const float*)d_in[1];
    p.Wh[0]   = (const float*)d_in[2];
    p.bias[0] = (const float*)d_in[3];
    p.Wx[1]   = (const float*)d_in[4];
    p.Wh[1]   = (const float*)d_in[5];
    p.bias[1] = (const float*)d_in[6];
    p.Wx[2]   = (const float*)d_in[7];
    p.Wh[2]   = (const float*)d_in[8];
    p.bias[2] = (const float*)d_in[9];
    p.Wx[3]   = (const float*)d_in[10];
    p.Wh[3]   = (const float*)d_in[11];
    p.bias[3] = (const float*)d_in[12];
    p.Y       = (float*)d_out;
    p.hbuf    = (float*)d_ws;
    p.ctr     = (unsigned int*)((char*)d_ws + (size_t)2 * BSZ * HH * sizeof(float));

    // ws is poisoned 0xAA before every timed launch: zero h0 double-buffer + counters
    init_ws<<<64, 256, 0, stream>>>(p.hbuf, p.ctr);

    lstm_persist<<<dim3(256), dim3(NT), 0, stream>>>(p);
}